// Round 22
// baseline (157.412 us; speedup 1.0000x reference)
//
#include <hip/hip_runtime.h>
#include <math.h>

#define GAMMA 0.05f
#define EPSBN 1e-5f

#define B_   128
#define H0   96
#define O1   32
#define P1   46   // pooled1 (46x46), conv1 out 92x92
#define O2   64
#define H2C  42   // conv2 out spatial
#define P2   21   // pooled2
#define FLAT (O2*P2*P2)   // 28224
#define L1N  256
#define NCLS 10
#define XW   104  // padded LDS row width (positions)
#define NSEG 21   // fc1 K-segments (1344 each = 3 x 448 chunks)

typedef __attribute__((ext_vector_type(8))) short bf16x8;
typedef __attribute__((ext_vector_type(4))) float f32x4;
typedef __attribute__((ext_vector_type(16))) float f32x16;

static __device__ __forceinline__ float bf2f(unsigned short h) {
    return __uint_as_float(((unsigned int)h) << 16);
}
static __device__ __forceinline__ unsigned short f2bf(float f) {
    unsigned int u = __float_as_uint(f);
    u = (u + 0x7FFFu + ((u >> 16) & 1u)) >> 16;
    return (unsigned short)u;
}

// ------- weight prep -------
// w2bf = -2*w2 [tap][ks][hi][o][8ch].
// w1q[s][o][e]: K-repacked conv1 weights (8 taps x 4 slots {x0,x1,x2,sq}).
__global__ void k_wprep(const float* __restrict__ w1, const float* __restrict__ w2,
                        unsigned short* __restrict__ w2bf, unsigned short* __restrict__ w1q,
                        float* __restrict__ wsq1, float* __restrict__ wsq2) {
    int pb = blockIdx.x;
    int tid = threadIdx.x;
    for (int i = pb * 256 + tid; i < 51200 + 4096; i += 64 * 256) {
        if (i < 51200) {
            int e = i & 7, o = (i >> 3) & 63, hi = (i >> 9) & 1, ks = (i >> 10) & 1, kp = i >> 11;
            int ch = ks * 16 + hi * 8 + e;
            w2bf[i] = f2bf(-2.f * w2[((size_t)o * 32 + ch) * 25 + kp]);
        } else {
            int j = i - 51200;
            int e = j & 7, o = (j >> 3) & 31, s = j >> 8;  // s 0..15
            int tap = (s >> 2) * 8 + 2 * (s & 3) + (e >> 2);
            int ch = e & 3;
            float v = 0.f;
            if (tap < 25) {
                if (ch < 3) v = -2.f * w1[(size_t)(o * 3 + ch) * 25 + tap];
                else v = 1.f;
            }
            w1q[j] = f2bf(v);
        }
    }
    if (pb == 0) {
        int lt = tid;
        if (lt < 32) {
            const float* p = w1 + lt * 75;
            float s = 0.f;
            for (int i = 0; i < 75; ++i) s += p[i] * p[i];
            wsq1[lt] = s;
        } else if (lt < 96) {
            const float* p = w2 + (size_t)(lt - 32) * 800;
            float s = 0.f;
            for (int i = 0; i < 800; ++i) s += p[i] * p[i];
            wsq2[lt - 32] = s;
        }
    }
}

// ------- conv1 MFMA v8: K repacked as 8 taps x 4 slots {x0,x1,x2,sq} -------
__global__ __launch_bounds__(256) void k_conv1m(
    const float* __restrict__ x, const unsigned short* __restrict__ w1q,
    const float* __restrict__ wsq1,
    const float* __restrict__ g, const float* __restrict__ bb_,
    const float* __restrict__ m, const float* __restrict__ v,
    unsigned short* __restrict__ h1t) {
    __shared__ unsigned short xt4[1536 * 4];  // 12288 B (valid 13*104=1352 positions)
    int b = blockIdx.y;
    int pi0 = blockIdx.x * 4;
    int tid = threadIdx.x;
    {
        const float* xb = x + (size_t)b * 3 * 9216;
        float va[6], vc[6], vd[6];
        int ok[6];
        #pragma unroll
        for (int it = 0; it < 6; ++it) {
            int c = tid + it * 256;
            int cs = c < 1352 ? c : 1351;
            int rr = cs / XW, cc2 = cs - rr * XW;
            int srow = 2 * pi0 + rr; if (srow > 95) srow = 95;
            ok[it] = (cc2 < 96);
            int off = srow * 96 + (cc2 < 96 ? cc2 : 95);
            va[it] = xb[off];
            vc[it] = xb[9216 + off];
            vd[it] = xb[18432 + off];
        }
        #pragma unroll
        for (int it = 0; it < 6; ++it) {
            int c = tid + it * 256;
            unsigned int p0 = 0, p1 = 0;
            if (ok[it]) {
                float a = va[it], cch = vc[it], dd = vd[it];
                float s = a * a + cch * cch + dd * dd;
                p0 = (unsigned)f2bf(a) | ((unsigned)f2bf(cch) << 16);
                p1 = (unsigned)f2bf(dd) | ((unsigned)f2bf(s) << 16);
            }
            uint2 pk; pk.x = p0; pk.y = p1;
            *(uint2*)(xt4 + (size_t)c * 4) = pk;
        }
    }
    __syncthreads();
    int w = tid >> 6, lane = tid & 63;
    int pi = pi0 + w;
    if (pi >= P1) return;
    int l15 = lane & 15, l4 = lane >> 4;

    int kiA[4], kjA[4], kiB[4], kjB[4];
    #pragma unroll
    for (int mm = 0; mm < 4; ++mm) {
        int tA = mm * 8 + 2 * l4;
        int tB = tA + 1;
        kiA[mm] = (tA < 25) ? tA / 5 : 4;  kjA[mm] = (tA < 25) ? tA % 5 : 4;
        kiB[mm] = (tB < 25) ? tB / 5 : 4;  kjB[mm] = (tB < 25) ? tB % 5 : 4;
    }
    bf16x8 Bq[4][2];
    #pragma unroll
    for (int mm = 0; mm < 4; ++mm)
        #pragma unroll
        for (int nt = 0; nt < 2; ++nt)
            Bq[mm][nt] = *(const bf16x8*)(w1q + (((size_t)(mm * 4 + l4)) * 32 + nt * 16 + l15) * 8);

    float wqa[2], sca[2], moa[2], boa[2];
    #pragma unroll
    for (int nt = 0; nt < 2; ++nt) {
        int o = nt * 16 + l15;
        wqa[nt] = wsq1[o];
        sca[nt] = g[o] * rsqrtf(v[o] + EPSBN);
        moa[nt] = m[o]; boa[nt] = bb_[o];
    }

    for (int s6 = 0; s6 < 6; ++s6) {
        int j0 = s6 * 16;
        f32x4 a0[2], a1[2];
        #pragma unroll
        for (int nt = 0; nt < 2; ++nt) {
            a0[nt] = (f32x4){0.f, 0.f, 0.f, 0.f};
            a1[nt] = (f32x4){0.f, 0.f, 0.f, 0.f};
        }
        {
            int r0 = 2 * w, r1 = 2 * w + 1;
            #pragma unroll
            for (int mm = 0; mm < 4; ++mm) {
                uint2 lo0 = *(const uint2*)(xt4 + ((size_t)(r0 + kiA[mm]) * XW + j0 + l15 + kjA[mm]) * 4);
                uint2 hi0 = *(const uint2*)(xt4 + ((size_t)(r0 + kiB[mm]) * XW + j0 + l15 + kjB[mm]) * 4);
                uint2 lo1 = *(const uint2*)(xt4 + ((size_t)(r1 + kiA[mm]) * XW + j0 + l15 + kjA[mm]) * 4);
                uint2 hi1 = *(const uint2*)(xt4 + ((size_t)(r1 + kiB[mm]) * XW + j0 + l15 + kjB[mm]) * 4);
                uint4 u0; u0.x = lo0.x; u0.y = lo0.y; u0.z = hi0.x; u0.w = hi0.y;
                uint4 u1; u1.x = lo1.x; u1.y = lo1.y; u1.z = hi1.x; u1.w = hi1.y;
                bf16x8 av0 = *(bf16x8*)&u0;
                bf16x8 av1 = *(bf16x8*)&u1;
                a0[0] = __builtin_amdgcn_mfma_f32_16x16x32_bf16(av0, Bq[mm][0], a0[0], 0, 0, 0);
                a0[1] = __builtin_amdgcn_mfma_f32_16x16x32_bf16(av0, Bq[mm][1], a0[1], 0, 0, 0);
                a1[0] = __builtin_amdgcn_mfma_f32_16x16x32_bf16(av1, Bq[mm][0], a1[0], 0, 0, 0);
                a1[1] = __builtin_amdgcn_mfma_f32_16x16x32_bf16(av1, Bq[mm][1], a1[1], 0, 0, 0);
            }
        }
        #pragma unroll
        for (int q = 0; q < 2; ++q) {
            int pj = (j0 >> 1) + l4 * 2 + q;   // pooled col
            if (pj < P1) {
                #pragma unroll
                for (int nt = 0; nt < 2; ++nt) {
                    float d00 = a0[nt][2 * q]     + wqa[nt];
                    float d01 = a0[nt][2 * q + 1] + wqa[nt];
                    float d10 = a1[nt][2 * q]     + wqa[nt];
                    float d11 = a1[nt][2 * q + 1] + wqa[nt];
                    float dm = fminf(fminf(d00, d01), fminf(d10, d11));
                    float y = (__expf(-GAMMA * dm) - moa[nt]) * sca[nt] + boa[nt];
                    h1t[((size_t)b * 2116 + pi * P1 + pj) * 32 + nt * 16 + l15] = f2bf(y);
                }
            }
        }
    }
}

// ------- conv2 MFMA: r19 proven version (12-row bands, in-LDS box; closed) -------
__global__ __launch_bounds__(256, 2) void k_conv2m(
    const unsigned short* __restrict__ h1t, const unsigned short* __restrict__ w2bf,
    const float* __restrict__ wsq2,
    const float* __restrict__ g2, const float* __restrict__ b2,
    const float* __restrict__ m2, const float* __restrict__ v2,
    unsigned short* __restrict__ h2t) {
    __shared__ unsigned short lds[2304 * 8];  // 36864 B (valid 12*46*4=2208 chunks)
    __shared__ float sst[12 * 46];
    __shared__ float rh[12 * 42];
    __shared__ float xq[8 * 42];
    int b = blockIdx.y;
    int bx = blockIdx.x;             // 0..5: pooled rows 4bx..4bx+3
    int rbase = 8 * bx;
    int tid = threadIdx.x;
    {
        uint4 tmp[9];
        #pragma unroll
        for (int it = 0; it < 9; ++it) {
            int c = tid + it * 256;
            int cs = c < 2208 ? c : 2207;
            int p = cs >> 2, s = cs & 3;
            int il = p / 46, jl = p - il * 46;
            int srow = rbase + il; if (srow > 45) srow = 45;
            int src_s = (s - il - jl) & 3;  // inverse swizzle on SOURCE side
            tmp[it] = *(const uint4*)(h1t + ((((size_t)b * 46 + srow) * 46 + jl) * 32) + src_s * 8);
        }
        #pragma unroll
        for (int it = 0; it < 9; ++it) {
            int c = tid + it * 256;
            *(uint4*)(lds + (size_t)c * 8) = tmp[it];
        }
    }
    __syncthreads();
    for (int p = tid; p < 552; p += 256) {
        float s2 = 0.f;
        #pragma unroll
        for (int sl = 0; sl < 4; ++sl) {
            bf16x8 v8 = *(const bf16x8*)(lds + (size_t)p * 32 + sl * 8);
            #pragma unroll
            for (int e = 0; e < 8; ++e) {
                float yv = bf2f((unsigned short)v8[e]);
                s2 = fmaf(yv, yv, s2);
            }
        }
        sst[p] = s2;
    }
    __syncthreads();
    for (int i = tid; i < 504; i += 256) {
        int r = i / 42, j = i - r * 42;
        const float* s = &sst[r * 46 + j];
        rh[i] = s[0] + s[1] + s[2] + s[3] + s[4];
    }
    __syncthreads();
    for (int i = tid; i < 336; i += 256) {
        const float* s = &rh[i];
        xq[i] = s[0] + s[42] + s[84] + s[126] + s[168];
    }
    __syncthreads();

    int lane = tid & 63, st = tid >> 6;   // 4 waves, one pooled row each
    int prow = 4 * bx + st;
    if (prow >= P2) return;
    int hi = lane >> 5;
    int ri = lane & 1;
    int cpos = (lane >> 1) & 15;
    int ol = lane & 31;

    float wqA[2], scA[2], moA[2], boA[2];
    #pragma unroll
    for (int nt = 0; nt < 2; ++nt) {
        int o = nt * 32 + ol;
        wqA[nt] = wsq2[o];
        scA[nt] = g2[o] * rsqrtf(v2[o] + EPSBN);
        moA[nt] = m2[o]; boA[nt] = b2[o];
    }

    f32x16 acc0[3], acc1[3];
    #pragma unroll
    for (int cg = 0; cg < 3; ++cg)
        #pragma unroll
        for (int e = 0; e < 16; ++e) { acc0[cg][e] = 0.f; acc1[cg][e] = 0.f; }

    #pragma unroll 1
    for (int ks = 0; ks < 2; ++ks) {
        const unsigned short* wb0 = w2bf + (((size_t)ks * 2 + hi) * 64 + ol) * 8;
        const unsigned short* wb1 = wb0 + 32 * 8;   // o + 32
        int sB = 2 * ks + hi;
        #pragma unroll 1
        for (int ki = 0; ki < 5; ++ki) {
            bf16x8 B0[5], B1[5];
            #pragma unroll
            for (int kj = 0; kj < 5; ++kj) {
                B0[kj] = *(const bf16x8*)(wb0 + (size_t)(ki * 5 + kj) * 2048);
                B1[kj] = *(const bf16x8*)(wb1 + (size_t)(ki * 5 + kj) * 2048);
            }
            int il = 2 * st + ri + ki;   // 0..11 local row
            int base = il * 46;
            int sI = sB + il;
            #pragma unroll
            for (int cg = 0; cg < 3; ++cg) {
                #pragma unroll
                for (int kj = 0; kj < 5; ++kj) {
                    int jl = cg * 16 + cpos + kj; if (jl > 45) jl = 45;
                    int slot = (sI + jl) & 3;
                    bf16x8 av = *(const bf16x8*)(lds + (base + jl) * 32 + slot * 8);
                    acc0[cg] = __builtin_amdgcn_mfma_f32_32x32x16_bf16(av, B0[kj], acc0[cg], 0, 0, 0);
                    acc1[cg] = __builtin_amdgcn_mfma_f32_32x32x16_bf16(av, B1[kj], acc1[cg], 0, 0, 0);
                }
            }
        }
    }
    size_t bb = (size_t)b * FLAT;
    int lr = 2 * st;
    #pragma unroll
    for (int cg = 0; cg < 3; ++cg) {
        int j0 = cg * 16;
        #pragma unroll
        for (int q = 0; q < 4; ++q) {
            int wdw = 2 * q + hi;
            int pcol = cg * 8 + wdw;
            if (pcol < P2) {
                int jc = j0 + 2 * wdw;
                float x00 = xq[lr * 42 + jc],       x01 = xq[lr * 42 + jc + 1];
                float x10 = xq[(lr + 1) * 42 + jc], x11 = xq[(lr + 1) * 42 + jc + 1];
                int pp = prow * 21 + pcol;
                {
                    float d0 = x00 + acc0[cg][4 * q + 0] + wqA[0];
                    float d1 = x10 + acc0[cg][4 * q + 1] + wqA[0];
                    float d2 = x01 + acc0[cg][4 * q + 2] + wqA[0];
                    float d3 = x11 + acc0[cg][4 * q + 3] + wqA[0];
                    float dm = fminf(fminf(d0, d1), fminf(d2, d3));
                    float y = (__expf(-GAMMA * dm) - moA[0]) * scA[0] + boA[0];
                    h2t[bb + (size_t)ol * 441 + pp] = f2bf(y);
                }
                {
                    float d0 = x00 + acc1[cg][4 * q + 0] + wqA[1];
                    float d1 = x10 + acc1[cg][4 * q + 1] + wqA[1];
                    float d2 = x01 + acc1[cg][4 * q + 2] + wqA[1];
                    float d3 = x11 + acc1[cg][4 * q + 3] + wqA[1];
                    float dm = fminf(fminf(d0, d1), fminf(d2, d3));
                    float y = (__expf(-GAMMA * dm) - moA[1]) * scA[1] + boA[1];
                    h2t[bb + (size_t)(32 + ol) * 441 + pp] = f2bf(y);
                }
            }
        }
    }
}

// ------- FC1 MFMA v4: 21 K-segments, 3 staged 448-chunks per block, persistent acc -------
// r22: part traffic 8.3 -> 2.75 MB; fewer blocks; MFMA math identical (k-order preserved).
__global__ __launch_bounds__(256) void k_fc1m(const unsigned short* __restrict__ A,
                                              const float* __restrict__ W,
                                              float* __restrict__ part) {
    __shared__ unsigned short Ws[64][456];
    int s = blockIdx.x;        // 0..20
    int nb = blockIdx.y;       // 0..3
    int n0 = nb * 64;
    int tid = threadIdx.x;
    int lane = tid & 63, w = tid >> 6;
    int l15 = lane & 15, l4 = lane >> 4;
    f32x4 acc[8];
    #pragma unroll
    for (int mf = 0; mf < 8; ++mf) acc[mf] = (f32x4){0.f, 0.f, 0.f, 0.f};

    #pragma unroll 1
    for (int cch = 0; cch < 3; ++cch) {
        int k0 = s * 1344 + cch * 448;
        if (cch) __syncthreads();
        for (int i = tid; i < 64 * 112; i += 256) {
            int n = i / 112, j = i - n * 112;
            float4 v = *(const float4*)(W + (size_t)(n0 + n) * FLAT + k0 + j * 4);
            unsigned int lo = (unsigned)f2bf(v.x) | ((unsigned)f2bf(v.y) << 16);
            unsigned int hi2 = (unsigned)f2bf(v.z) | ((unsigned)f2bf(v.w) << 16);
            uint2 pk; pk.x = lo; pk.y = hi2;
            *(uint2*)(&Ws[n][j * 4]) = pk;
        }
        __syncthreads();
        const unsigned short* ap = A + (size_t)l15 * FLAT + k0 + l4 * 8;
        #pragma unroll 2
        for (int kc = 0; kc < 14; ++kc) {
            bf16x8 Bf = *(const bf16x8*)(&Ws[w * 16 + l15][kc * 32 + l4 * 8]);
            #pragma unroll
            for (int mf = 0; mf < 8; ++mf) {
                bf16x8 Af = *(const bf16x8*)(ap + (size_t)mf * 16 * FLAT + kc * 32);
                acc[mf] = __builtin_amdgcn_mfma_f32_16x16x32_bf16(Af, Bf, acc[mf], 0, 0, 0);
            }
        }
    }
    float* pp = part + (size_t)s * B_ * L1N;
    #pragma unroll
    for (int mf = 0; mf < 8; ++mf)
        #pragma unroll
        for (int r = 0; r < 4; ++r)
            pp[(size_t)(mf * 16 + l4 * 4 + r) * L1N + n0 + w * 16 + l15] = acc[mf][r];
}

// ---------------- FC1 reduce + bias + relu ----------------
__global__ void k_fc1red(const float* __restrict__ part, const float* __restrict__ bias,
                         float* __restrict__ fc1o) {
    int idx = blockIdx.x * blockDim.x + threadIdx.x;
    if (idx >= B_ * L1N) return;
    int o = idx & (L1N - 1);
    float s = 0.f;
    #pragma unroll
    for (int ks = 0; ks < NSEG; ++ks) s += part[(size_t)ks * B_ * L1N + idx];
    fc1o[idx] = fmaxf(s + bias[o], 0.f);
}

// ---------------- FC2 + relu + log_softmax ----------------
__global__ void k_fc2(const float* __restrict__ a, const float* __restrict__ w,
                      const float* __restrict__ bias, float* __restrict__ out) {
    int b = blockIdx.x;
    int lane = threadIdx.x;  // 64
    __shared__ float z[NCLS];
    for (int j = 0; j < NCLS; ++j) {
        float p = 0.f;
        for (int k = lane; k < L1N; k += 64)
            p = fmaf(a[(size_t)b * L1N + k], w[(size_t)j * L1N + k], p);
        #pragma unroll
        for (int off = 32; off; off >>= 1) p += __shfl_down(p, off, 64);
        if (lane == 0) z[j] = fmaxf(p + bias[j], 0.f);
    }
    __syncthreads();
    if (lane == 0) {
        float mx = -1e30f;
        for (int j = 0; j < NCLS; ++j) mx = fmaxf(mx, z[j]);
        float s = 0.f;
        for (int j = 0; j < NCLS; ++j) s += expf(z[j] - mx);
        float l = logf(s);
        for (int j = 0; j < NCLS; ++j) out[(size_t)b * NCLS + j] = z[j] - mx - l;
    }
}

extern "C" void kernel_launch(void* const* d_in, const int* in_sizes, int n_in,
                              void* d_out, int out_size, void* d_ws, size_t ws_size,
                              hipStream_t stream) {
    const float* x    = (const float*)d_in[0];
    const float* w1   = (const float*)d_in[1];
    const float* w2   = (const float*)d_in[2];
    const float* bn1g = (const float*)d_in[3];
    const float* bn1b = (const float*)d_in[4];
    const float* bn1m = (const float*)d_in[5];
    const float* bn1v = (const float*)d_in[6];
    const float* bn2g = (const float*)d_in[7];
    const float* bn2b = (const float*)d_in[8];
    const float* bn2m = (const float*)d_in[9];
    const float* bn2v = (const float*)d_in[10];
    const float* fc1w = (const float*)d_in[11];
    const float* fc1b = (const float*)d_in[12];
    const float* fc2w = (const float*)d_in[13];
    const float* fc2b = (const float*)d_in[14];
    float* out = (float*)d_out;

    char* wsb = (char*)d_ws;
    unsigned short* h1t = (unsigned short*)wsb;  wsb += (size_t)B_ * 2116 * 32 * 2;     // 17.3 MB
    unsigned short* h2t = (unsigned short*)wsb;  wsb += (size_t)B_ * FLAT * 2;          // 7.2 MB (o-major)
    float* part  = (float*)wsb;                  wsb += (size_t)NSEG * B_ * L1N * 4;    // 2.75 MB
    float* fc1o  = (float*)wsb;                  wsb += (size_t)B_ * L1N * 4;
    unsigned short* w2bf = (unsigned short*)wsb; wsb += (size_t)51200 * 2;
    unsigned short* w1q  = (unsigned short*)wsb; wsb += (size_t)4096 * 2;
    float* wsq1 = (float*)wsb;                   wsb += 32 * 4;
    float* wsq2 = (float*)wsb;                   wsb += 64 * 4;

    k_wprep<<<64, 256, 0, stream>>>(w1, w2, w2bf, w1q, wsq1, wsq2);
    k_conv1m<<<dim3(12, B_), 256, 0, stream>>>(
        x, w1q, wsq1, bn1g, bn1b, bn1m, bn1v, h1t);
    k_conv2m<<<dim3(6, B_), 256, 0, stream>>>(
        h1t, w2bf, wsq2, bn2g, bn2b, bn2m, bn2v, h2t);
    k_fc1m<<<dim3(NSEG, 4), 256, 0, stream>>>(h2t, fc1w, part);
    k_fc1red<<<(B_ * L1N + 255) / 256, 256, 0, stream>>>(part, fc1b, fc1o);
    k_fc2<<<B_, 64, 0, stream>>>(fc1o, fc2w, fc2b, out);
}

// Round 23
// 105.702 us; speedup vs baseline: 1.4892x; 1.4892x over previous
//
#include <hip/hip_runtime.h>
#include <math.h>

#define GAMMA 0.05f
#define EPSBN 1e-5f

#define B_   128
#define H0   96
#define O1   32
#define P1   46   // pooled1 (46x46), conv1 out 92x92
#define O2   64
#define H2C  42   // conv2 out spatial
#define P2   21   // pooled2
#define FLAT (O2*P2*P2)   // 28224
#define L1N  256
#define NCLS 10
#define XW   104  // padded LDS row width (positions)

typedef __attribute__((ext_vector_type(8))) short bf16x8;
typedef __attribute__((ext_vector_type(4))) float f32x4;
typedef __attribute__((ext_vector_type(16))) float f32x16;

static __device__ __forceinline__ float bf2f(unsigned short h) {
    return __uint_as_float(((unsigned int)h) << 16);
}
static __device__ __forceinline__ unsigned short f2bf(float f) {
    unsigned int u = __float_as_uint(f);
    u = (u + 0x7FFFu + ((u >> 16) & 1u)) >> 16;
    return (unsigned short)u;
}

// ------- weight prep -------
__global__ void k_wprep(const float* __restrict__ w1, const float* __restrict__ w2,
                        unsigned short* __restrict__ w2bf, unsigned short* __restrict__ w1q,
                        float* __restrict__ wsq1, float* __restrict__ wsq2) {
    int pb = blockIdx.x;
    int tid = threadIdx.x;
    for (int i = pb * 256 + tid; i < 51200 + 4096; i += 64 * 256) {
        if (i < 51200) {
            int e = i & 7, o = (i >> 3) & 63, hi = (i >> 9) & 1, ks = (i >> 10) & 1, kp = i >> 11;
            int ch = ks * 16 + hi * 8 + e;
            w2bf[i] = f2bf(-2.f * w2[((size_t)o * 32 + ch) * 25 + kp]);
        } else {
            int j = i - 51200;
            int e = j & 7, o = (j >> 3) & 31, s = j >> 8;  // s 0..15
            int tap = (s >> 2) * 8 + 2 * (s & 3) + (e >> 2);
            int ch = e & 3;
            float v = 0.f;
            if (tap < 25) {
                if (ch < 3) v = -2.f * w1[(size_t)(o * 3 + ch) * 25 + tap];
                else v = 1.f;
            }
            w1q[j] = f2bf(v);
        }
    }
    if (pb == 0) {
        int lt = tid;
        if (lt < 32) {
            const float* p = w1 + lt * 75;
            float s = 0.f;
            for (int i = 0; i < 75; ++i) s += p[i] * p[i];
            wsq1[lt] = s;
        } else if (lt < 96) {
            const float* p = w2 + (size_t)(lt - 32) * 800;
            float s = 0.f;
            for (int i = 0; i < 800; ++i) s += p[i] * p[i];
            wsq2[lt - 32] = s;
        }
    }
}

// ------- conv1 MFMA v8: K repacked as 8 taps x 4 slots {x0,x1,x2,sq} -------
__global__ __launch_bounds__(256) void k_conv1m(
    const float* __restrict__ x, const unsigned short* __restrict__ w1q,
    const float* __restrict__ wsq1,
    const float* __restrict__ g, const float* __restrict__ bb_,
    const float* __restrict__ m, const float* __restrict__ v,
    unsigned short* __restrict__ h1t) {
    __shared__ unsigned short xt4[1536 * 4];  // 12288 B (valid 13*104=1352 positions)
    int b = blockIdx.y;
    int pi0 = blockIdx.x * 4;
    int tid = threadIdx.x;
    {
        const float* xb = x + (size_t)b * 3 * 9216;
        float va[6], vc[6], vd[6];
        int ok[6];
        #pragma unroll
        for (int it = 0; it < 6; ++it) {
            int c = tid + it * 256;
            int cs = c < 1352 ? c : 1351;
            int rr = cs / XW, cc2 = cs - rr * XW;
            int srow = 2 * pi0 + rr; if (srow > 95) srow = 95;
            ok[it] = (cc2 < 96);
            int off = srow * 96 + (cc2 < 96 ? cc2 : 95);
            va[it] = xb[off];
            vc[it] = xb[9216 + off];
            vd[it] = xb[18432 + off];
        }
        #pragma unroll
        for (int it = 0; it < 6; ++it) {
            int c = tid + it * 256;
            unsigned int p0 = 0, p1 = 0;
            if (ok[it]) {
                float a = va[it], cch = vc[it], dd = vd[it];
                float s = a * a + cch * cch + dd * dd;
                p0 = (unsigned)f2bf(a) | ((unsigned)f2bf(cch) << 16);
                p1 = (unsigned)f2bf(dd) | ((unsigned)f2bf(s) << 16);
            }
            uint2 pk; pk.x = p0; pk.y = p1;
            *(uint2*)(xt4 + (size_t)c * 4) = pk;
        }
    }
    __syncthreads();
    int w = tid >> 6, lane = tid & 63;
    int pi = pi0 + w;
    if (pi >= P1) return;
    int l15 = lane & 15, l4 = lane >> 4;

    int kiA[4], kjA[4], kiB[4], kjB[4];
    #pragma unroll
    for (int mm = 0; mm < 4; ++mm) {
        int tA = mm * 8 + 2 * l4;
        int tB = tA + 1;
        kiA[mm] = (tA < 25) ? tA / 5 : 4;  kjA[mm] = (tA < 25) ? tA % 5 : 4;
        kiB[mm] = (tB < 25) ? tB / 5 : 4;  kjB[mm] = (tB < 25) ? tB % 5 : 4;
    }
    bf16x8 Bq[4][2];
    #pragma unroll
    for (int mm = 0; mm < 4; ++mm)
        #pragma unroll
        for (int nt = 0; nt < 2; ++nt)
            Bq[mm][nt] = *(const bf16x8*)(w1q + (((size_t)(mm * 4 + l4)) * 32 + nt * 16 + l15) * 8);

    float wqa[2], sca[2], moa[2], boa[2];
    #pragma unroll
    for (int nt = 0; nt < 2; ++nt) {
        int o = nt * 16 + l15;
        wqa[nt] = wsq1[o];
        sca[nt] = g[o] * rsqrtf(v[o] + EPSBN);
        moa[nt] = m[o]; boa[nt] = bb_[o];
    }

    for (int s6 = 0; s6 < 6; ++s6) {
        int j0 = s6 * 16;
        f32x4 a0[2], a1[2];
        #pragma unroll
        for (int nt = 0; nt < 2; ++nt) {
            a0[nt] = (f32x4){0.f, 0.f, 0.f, 0.f};
            a1[nt] = (f32x4){0.f, 0.f, 0.f, 0.f};
        }
        {
            int r0 = 2 * w, r1 = 2 * w + 1;
            #pragma unroll
            for (int mm = 0; mm < 4; ++mm) {
                uint2 lo0 = *(const uint2*)(xt4 + ((size_t)(r0 + kiA[mm]) * XW + j0 + l15 + kjA[mm]) * 4);
                uint2 hi0 = *(const uint2*)(xt4 + ((size_t)(r0 + kiB[mm]) * XW + j0 + l15 + kjB[mm]) * 4);
                uint2 lo1 = *(const uint2*)(xt4 + ((size_t)(r1 + kiA[mm]) * XW + j0 + l15 + kjA[mm]) * 4);
                uint2 hi1 = *(const uint2*)(xt4 + ((size_t)(r1 + kiB[mm]) * XW + j0 + l15 + kjB[mm]) * 4);
                uint4 u0; u0.x = lo0.x; u0.y = lo0.y; u0.z = hi0.x; u0.w = hi0.y;
                uint4 u1; u1.x = lo1.x; u1.y = lo1.y; u1.z = hi1.x; u1.w = hi1.y;
                bf16x8 av0 = *(bf16x8*)&u0;
                bf16x8 av1 = *(bf16x8*)&u1;
                a0[0] = __builtin_amdgcn_mfma_f32_16x16x32_bf16(av0, Bq[mm][0], a0[0], 0, 0, 0);
                a0[1] = __builtin_amdgcn_mfma_f32_16x16x32_bf16(av0, Bq[mm][1], a0[1], 0, 0, 0);
                a1[0] = __builtin_amdgcn_mfma_f32_16x16x32_bf16(av1, Bq[mm][0], a1[0], 0, 0, 0);
                a1[1] = __builtin_amdgcn_mfma_f32_16x16x32_bf16(av1, Bq[mm][1], a1[1], 0, 0, 0);
            }
        }
        #pragma unroll
        for (int q = 0; q < 2; ++q) {
            int pj = (j0 >> 1) + l4 * 2 + q;   // pooled col
            if (pj < P1) {
                #pragma unroll
                for (int nt = 0; nt < 2; ++nt) {
                    float d00 = a0[nt][2 * q]     + wqa[nt];
                    float d01 = a0[nt][2 * q + 1] + wqa[nt];
                    float d10 = a1[nt][2 * q]     + wqa[nt];
                    float d11 = a1[nt][2 * q + 1] + wqa[nt];
                    float dm = fminf(fminf(d00, d01), fminf(d10, d11));
                    float y = (__expf(-GAMMA * dm) - moa[nt]) * sca[nt] + boa[nt];
                    h1t[((size_t)b * 2116 + pi * P1 + pj) * 32 + nt * 16 + l15] = f2bf(y);
                }
            }
        }
    }
}

// ------- conv2 MFMA: r19 proven version (12-row bands, in-LDS box; closed) -------
__global__ __launch_bounds__(256, 2) void k_conv2m(
    const unsigned short* __restrict__ h1t, const unsigned short* __restrict__ w2bf,
    const float* __restrict__ wsq2,
    const float* __restrict__ g2, const float* __restrict__ b2,
    const float* __restrict__ m2, const float* __restrict__ v2,
    unsigned short* __restrict__ h2t) {
    __shared__ unsigned short lds[2304 * 8];  // 36864 B (valid 12*46*4=2208 chunks)
    __shared__ float sst[12 * 46];
    __shared__ float rh[12 * 42];
    __shared__ float xq[8 * 42];
    int b = blockIdx.y;
    int bx = blockIdx.x;             // 0..5: pooled rows 4bx..4bx+3
    int rbase = 8 * bx;
    int tid = threadIdx.x;
    {
        uint4 tmp[9];
        #pragma unroll
        for (int it = 0; it < 9; ++it) {
            int c = tid + it * 256;
            int cs = c < 2208 ? c : 2207;
            int p = cs >> 2, s = cs & 3;
            int il = p / 46, jl = p - il * 46;
            int srow = rbase + il; if (srow > 45) srow = 45;
            int src_s = (s - il - jl) & 3;  // inverse swizzle on SOURCE side
            tmp[it] = *(const uint4*)(h1t + ((((size_t)b * 46 + srow) * 46 + jl) * 32) + src_s * 8);
        }
        #pragma unroll
        for (int it = 0; it < 9; ++it) {
            int c = tid + it * 256;
            *(uint4*)(lds + (size_t)c * 8) = tmp[it];
        }
    }
    __syncthreads();
    for (int p = tid; p < 552; p += 256) {
        float s2 = 0.f;
        #pragma unroll
        for (int sl = 0; sl < 4; ++sl) {
            bf16x8 v8 = *(const bf16x8*)(lds + (size_t)p * 32 + sl * 8);
            #pragma unroll
            for (int e = 0; e < 8; ++e) {
                float yv = bf2f((unsigned short)v8[e]);
                s2 = fmaf(yv, yv, s2);
            }
        }
        sst[p] = s2;
    }
    __syncthreads();
    for (int i = tid; i < 504; i += 256) {
        int r = i / 42, j = i - r * 42;
        const float* s = &sst[r * 46 + j];
        rh[i] = s[0] + s[1] + s[2] + s[3] + s[4];
    }
    __syncthreads();
    for (int i = tid; i < 336; i += 256) {
        const float* s = &rh[i];
        xq[i] = s[0] + s[42] + s[84] + s[126] + s[168];
    }
    __syncthreads();

    int lane = tid & 63, st = tid >> 6;   // 4 waves, one pooled row each
    int prow = 4 * bx + st;
    if (prow >= P2) return;
    int hi = lane >> 5;
    int ri = lane & 1;
    int cpos = (lane >> 1) & 15;
    int ol = lane & 31;

    float wqA[2], scA[2], moA[2], boA[2];
    #pragma unroll
    for (int nt = 0; nt < 2; ++nt) {
        int o = nt * 32 + ol;
        wqA[nt] = wsq2[o];
        scA[nt] = g2[o] * rsqrtf(v2[o] + EPSBN);
        moA[nt] = m2[o]; boA[nt] = b2[o];
    }

    f32x16 acc0[3], acc1[3];
    #pragma unroll
    for (int cg = 0; cg < 3; ++cg)
        #pragma unroll
        for (int e = 0; e < 16; ++e) { acc0[cg][e] = 0.f; acc1[cg][e] = 0.f; }

    #pragma unroll 1
    for (int ks = 0; ks < 2; ++ks) {
        const unsigned short* wb0 = w2bf + (((size_t)ks * 2 + hi) * 64 + ol) * 8;
        const unsigned short* wb1 = wb0 + 32 * 8;   // o + 32
        int sB = 2 * ks + hi;
        #pragma unroll 1
        for (int ki = 0; ki < 5; ++ki) {
            bf16x8 B0[5], B1[5];
            #pragma unroll
            for (int kj = 0; kj < 5; ++kj) {
                B0[kj] = *(const bf16x8*)(wb0 + (size_t)(ki * 5 + kj) * 2048);
                B1[kj] = *(const bf16x8*)(wb1 + (size_t)(ki * 5 + kj) * 2048);
            }
            int il = 2 * st + ri + ki;   // 0..11 local row
            int base = il * 46;
            int sI = sB + il;
            #pragma unroll
            for (int cg = 0; cg < 3; ++cg) {
                #pragma unroll
                for (int kj = 0; kj < 5; ++kj) {
                    int jl = cg * 16 + cpos + kj; if (jl > 45) jl = 45;
                    int slot = (sI + jl) & 3;
                    bf16x8 av = *(const bf16x8*)(lds + (base + jl) * 32 + slot * 8);
                    acc0[cg] = __builtin_amdgcn_mfma_f32_32x32x16_bf16(av, B0[kj], acc0[cg], 0, 0, 0);
                    acc1[cg] = __builtin_amdgcn_mfma_f32_32x32x16_bf16(av, B1[kj], acc1[cg], 0, 0, 0);
                }
            }
        }
    }
    size_t bb = (size_t)b * FLAT;
    int lr = 2 * st;
    #pragma unroll
    for (int cg = 0; cg < 3; ++cg) {
        int j0 = cg * 16;
        #pragma unroll
        for (int q = 0; q < 4; ++q) {
            int wdw = 2 * q + hi;
            int pcol = cg * 8 + wdw;
            if (pcol < P2) {
                int jc = j0 + 2 * wdw;
                float x00 = xq[lr * 42 + jc],       x01 = xq[lr * 42 + jc + 1];
                float x10 = xq[(lr + 1) * 42 + jc], x11 = xq[(lr + 1) * 42 + jc + 1];
                int pp = prow * 21 + pcol;
                {
                    float d0 = x00 + acc0[cg][4 * q + 0] + wqA[0];
                    float d1 = x10 + acc0[cg][4 * q + 1] + wqA[0];
                    float d2 = x01 + acc0[cg][4 * q + 2] + wqA[0];
                    float d3 = x11 + acc0[cg][4 * q + 3] + wqA[0];
                    float dm = fminf(fminf(d0, d1), fminf(d2, d3));
                    float y = (__expf(-GAMMA * dm) - moA[0]) * scA[0] + boA[0];
                    h2t[bb + (size_t)ol * 441 + pp] = f2bf(y);
                }
                {
                    float d0 = x00 + acc1[cg][4 * q + 0] + wqA[1];
                    float d1 = x10 + acc1[cg][4 * q + 1] + wqA[1];
                    float d2 = x01 + acc1[cg][4 * q + 2] + wqA[1];
                    float d3 = x11 + acc1[cg][4 * q + 3] + wqA[1];
                    float dm = fminf(fminf(d0, d1), fminf(d2, d3));
                    float y = (__expf(-GAMMA * dm) - moA[1]) * scA[1] + boA[1];
                    h2t[bb + (size_t)(32 + ol) * 441 + pp] = f2bf(y);
                }
            }
        }
    }
}

// ------- FC1 MFMA v3 (r21 proven): 63 K-segments, grid (63,4) = 252 blocks -------
// r22 lesson: NSEG=21 (84 blocks) starved the CUs (Occ 3.5%, fc1m 87us). Reverted.
__global__ __launch_bounds__(256) void k_fc1m(const unsigned short* __restrict__ A,
                                              const float* __restrict__ W,
                                              float* __restrict__ part) {
    __shared__ unsigned short Ws[64][456];
    int s = blockIdx.x;
    int nb = blockIdx.y;
    int n0 = nb * 64;
    int k0 = s * 448;
    int tid = threadIdx.x;
    for (int i = tid; i < 64 * 112; i += 256) {
        int n = i / 112, j = i - n * 112;
        float4 v = *(const float4*)(W + (size_t)(n0 + n) * FLAT + k0 + j * 4);
        unsigned int lo = (unsigned)f2bf(v.x) | ((unsigned)f2bf(v.y) << 16);
        unsigned int hi2 = (unsigned)f2bf(v.z) | ((unsigned)f2bf(v.w) << 16);
        uint2 pk; pk.x = lo; pk.y = hi2;
        *(uint2*)(&Ws[n][j * 4]) = pk;
    }
    __syncthreads();
    int lane = tid & 63, w = tid >> 6;
    int l15 = lane & 15, l4 = lane >> 4;
    const unsigned short* ap = A + (size_t)l15 * FLAT + k0 + l4 * 8;
    f32x4 acc[8];
    #pragma unroll
    for (int mf = 0; mf < 8; ++mf) acc[mf] = (f32x4){0.f, 0.f, 0.f, 0.f};
    #pragma unroll 2
    for (int kc = 0; kc < 14; ++kc) {
        bf16x8 Bf = *(const bf16x8*)(&Ws[w * 16 + l15][kc * 32 + l4 * 8]);
        #pragma unroll
        for (int mf = 0; mf < 8; ++mf) {
            bf16x8 Af = *(const bf16x8*)(ap + (size_t)mf * 16 * FLAT + kc * 32);
            acc[mf] = __builtin_amdgcn_mfma_f32_16x16x32_bf16(Af, Bf, acc[mf], 0, 0, 0);
        }
    }
    float* pp = part + (size_t)s * B_ * L1N;
    #pragma unroll
    for (int mf = 0; mf < 8; ++mf)
        #pragma unroll
        for (int r = 0; r < 4; ++r)
            pp[(size_t)(mf * 16 + l4 * 4 + r) * L1N + n0 + w * 16 + l15] = acc[mf][r];
}

// ------- fused FC1-reduce + FC2 + log_softmax: one block per image -------
__global__ __launch_bounds__(256) void k_fcout(const float* __restrict__ part,
                                               const float* __restrict__ fc1b,
                                               const float* __restrict__ fc2w,
                                               const float* __restrict__ fc2b,
                                               float* __restrict__ out) {
    __shared__ float a[L1N];
    __shared__ float z[16];
    int b = blockIdx.x;
    int o = threadIdx.x;
    float s = 0.f;
    for (int ks = 0; ks < 63; ++ks) s += part[(size_t)ks * B_ * L1N + (size_t)b * L1N + o];
    a[o] = fmaxf(s + fc1b[o], 0.f);
    __syncthreads();
    int lane = threadIdx.x & 63, wv = threadIdx.x >> 6;
    for (int j = wv; j < NCLS; j += 4) {
        float p = 0.f;
        for (int k = lane; k < L1N; k += 64)
            p = fmaf(a[k], fc2w[(size_t)j * L1N + k], p);
        #pragma unroll
        for (int off = 32; off; off >>= 1) p += __shfl_down(p, off, 64);
        if (lane == 0) z[j] = fmaxf(p + fc2b[j], 0.f);
    }
    __syncthreads();
    if (threadIdx.x == 0) {
        float mx = -1e30f;
        for (int j = 0; j < NCLS; ++j) mx = fmaxf(mx, z[j]);
        float ss = 0.f;
        for (int j = 0; j < NCLS; ++j) ss += expf(z[j] - mx);
        float l = logf(ss);
        for (int j = 0; j < NCLS; ++j) out[(size_t)b * NCLS + j] = z[j] - mx - l;
    }
}

extern "C" void kernel_launch(void* const* d_in, const int* in_sizes, int n_in,
                              void* d_out, int out_size, void* d_ws, size_t ws_size,
                              hipStream_t stream) {
    const float* x    = (const float*)d_in[0];
    const float* w1   = (const float*)d_in[1];
    const float* w2   = (const float*)d_in[2];
    const float* bn1g = (const float*)d_in[3];
    const float* bn1b = (const float*)d_in[4];
    const float* bn1m = (const float*)d_in[5];
    const float* bn1v = (const float*)d_in[6];
    const float* bn2g = (const float*)d_in[7];
    const float* bn2b = (const float*)d_in[8];
    const float* bn2m = (const float*)d_in[9];
    const float* bn2v = (const float*)d_in[10];
    const float* fc1w = (const float*)d_in[11];
    const float* fc1b = (const float*)d_in[12];
    const float* fc2w = (const float*)d_in[13];
    const float* fc2b = (const float*)d_in[14];
    float* out = (float*)d_out;

    char* wsb = (char*)d_ws;
    unsigned short* h1t = (unsigned short*)wsb;  wsb += (size_t)B_ * 2116 * 32 * 2;     // 17.3 MB
    unsigned short* h2t = (unsigned short*)wsb;  wsb += (size_t)B_ * FLAT * 2;          // 7.2 MB (o-major)
    float* part  = (float*)wsb;                  wsb += (size_t)63 * B_ * L1N * 4;      // 8.3 MB
    unsigned short* w2bf = (unsigned short*)wsb; wsb += (size_t)51200 * 2;
    unsigned short* w1q  = (unsigned short*)wsb; wsb += (size_t)4096 * 2;
    float* wsq1 = (float*)wsb;                   wsb += 32 * 4;
    float* wsq2 = (float*)wsb;                   wsb += 64 * 4;

    k_wprep<<<64, 256, 0, stream>>>(w1, w2, w2bf, w1q, wsq1, wsq2);
    k_conv1m<<<dim3(12, B_), 256, 0, stream>>>(
        x, w1q, wsq1, bn1g, bn1b, bn1m, bn1v, h1t);
    k_conv2m<<<dim3(6, B_), 256, 0, stream>>>(
        h1t, w2bf, wsq2, bn2g, bn2b, bn2m, bn2v, h2t);
    k_fc1m<<<dim3(63, 4), 256, 0, stream>>>(h2t, fc1w, part);
    k_fcout<<<B_, 256, 0, stream>>>(part, fc1b, fc2w, fc2b, out);
}

// Round 24
// 95.929 us; speedup vs baseline: 1.6409x; 1.1019x over previous
//
#include <hip/hip_runtime.h>
#include <math.h>

#define GAMMA 0.05f
#define EPSBN 1e-5f

#define B_   128
#define H0   96
#define O1   32
#define P1   46   // pooled1 (46x46), conv1 out 92x92
#define O2   64
#define H2C  42   // conv2 out spatial
#define P2   21   // pooled2
#define FLAT (O2*P2*P2)   // 28224
#define L1N  256
#define NCLS 10
#define XW   104  // padded LDS row width (positions)

typedef __attribute__((ext_vector_type(8))) short bf16x8;
typedef __attribute__((ext_vector_type(4))) float f32x4;
typedef __attribute__((ext_vector_type(16))) float f32x16;

static __device__ __forceinline__ float bf2f(unsigned short h) {
    return __uint_as_float(((unsigned int)h) << 16);
}
static __device__ __forceinline__ unsigned short f2bf(float f) {
    unsigned int u = __float_as_uint(f);
    u = (u + 0x7FFFu + ((u >> 16) & 1u)) >> 16;
    return (unsigned short)u;
}

// ------- conv1 MFMA v9: inline w1q/wsq1 prep (per block, LDS); w2bf prep in bx==12 blocks -------
// r24: k_wprep launch deleted. w1 is 9.6KB (L1-resident) so per-block recompute of
// w1q (4096 bf16) + wsq1 (32 f32) is free under staging. w2bf/wsq2 for conv2m are
// produced by 64 extra blocks (bx==12); consumed only after the kernel boundary.
__global__ __launch_bounds__(256) void k_conv1m(
    const float* __restrict__ x, const float* __restrict__ w1, const float* __restrict__ w2,
    const float* __restrict__ g, const float* __restrict__ bb_,
    const float* __restrict__ m, const float* __restrict__ v,
    unsigned short* __restrict__ h1t,
    unsigned short* __restrict__ w2bf, float* __restrict__ wsq2) {
    int b = blockIdx.y;
    int tid = threadIdx.x;
    if (blockIdx.x == 12) {
        // weight prep for conv2m (64 active blocks)
        int pb = b;
        if (pb < 64) {
            for (int i = pb * 256 + tid; i < 51200; i += 64 * 256) {
                int e = i & 7, o = (i >> 3) & 63, hi = (i >> 9) & 1, ks = (i >> 10) & 1, kp = i >> 11;
                int ch = ks * 16 + hi * 8 + e;
                w2bf[i] = f2bf(-2.f * w2[((size_t)o * 32 + ch) * 25 + kp]);
            }
            if (pb == 0 && tid < 64) {
                const float* p = w2 + (size_t)tid * 800;
                float s = 0.f;
                for (int i = 0; i < 800; ++i) s += p[i] * p[i];
                wsq2[tid] = s;
            }
        }
        return;
    }
    __shared__ unsigned short xt4[1536 * 4];  // 12288 B (valid 13*104=1352 positions)
    __shared__ unsigned short w1qs[4096];     // 8192 B
    __shared__ float wsq1s[32];
    int pi0 = blockIdx.x * 4;
    {
        const float* xb = x + (size_t)b * 3 * 9216;
        float va[6], vc[6], vd[6];
        int ok[6];
        #pragma unroll
        for (int it = 0; it < 6; ++it) {
            int c = tid + it * 256;
            int cs = c < 1352 ? c : 1351;
            int rr = cs / XW, cc2 = cs - rr * XW;
            int srow = 2 * pi0 + rr; if (srow > 95) srow = 95;
            ok[it] = (cc2 < 96);
            int off = srow * 96 + (cc2 < 96 ? cc2 : 95);
            va[it] = xb[off];
            vc[it] = xb[9216 + off];
            vd[it] = xb[18432 + off];
        }
        #pragma unroll
        for (int it = 0; it < 6; ++it) {
            int c = tid + it * 256;
            unsigned int p0 = 0, p1 = 0;
            if (ok[it]) {
                float a = va[it], cch = vc[it], dd = vd[it];
                float s = a * a + cch * cch + dd * dd;
                p0 = (unsigned)f2bf(a) | ((unsigned)f2bf(cch) << 16);
                p1 = (unsigned)f2bf(dd) | ((unsigned)f2bf(s) << 16);
            }
            uint2 pk; pk.x = p0; pk.y = p1;
            *(uint2*)(xt4 + (size_t)c * 4) = pk;
        }
        // inline w1q prep (K repacked: 8 taps x 4 slots {x0,x1,x2,sq})
        for (int j = tid; j < 4096; j += 256) {
            int e = j & 7, o = (j >> 3) & 31, s = j >> 8;  // s 0..15
            int tap = (s >> 2) * 8 + 2 * (s & 3) + (e >> 2);
            int ch = e & 3;
            float vv = 0.f;
            if (tap < 25) {
                if (ch < 3) vv = -2.f * w1[(size_t)(o * 3 + ch) * 25 + tap];
                else vv = 1.f;
            }
            w1qs[j] = f2bf(vv);
        }
        if (tid < 32) {
            const float* p = w1 + tid * 75;
            float s = 0.f;
            for (int i = 0; i < 75; ++i) s += p[i] * p[i];
            wsq1s[tid] = s;
        }
    }
    __syncthreads();
    int w = tid >> 6, lane = tid & 63;
    int pi = pi0 + w;
    if (pi >= P1) return;
    int l15 = lane & 15, l4 = lane >> 4;

    int kiA[4], kjA[4], kiB[4], kjB[4];
    #pragma unroll
    for (int mm = 0; mm < 4; ++mm) {
        int tA = mm * 8 + 2 * l4;
        int tB = tA + 1;
        kiA[mm] = (tA < 25) ? tA / 5 : 4;  kjA[mm] = (tA < 25) ? tA % 5 : 4;
        kiB[mm] = (tB < 25) ? tB / 5 : 4;  kjB[mm] = (tB < 25) ? tB % 5 : 4;
    }
    bf16x8 Bq[4][2];
    #pragma unroll
    for (int mm = 0; mm < 4; ++mm)
        #pragma unroll
        for (int nt = 0; nt < 2; ++nt)
            Bq[mm][nt] = *(const bf16x8*)(&w1qs[(((size_t)(mm * 4 + l4)) * 32 + nt * 16 + l15) * 8]);

    float wqa[2], sca[2], moa[2], boa[2];
    #pragma unroll
    for (int nt = 0; nt < 2; ++nt) {
        int o = nt * 16 + l15;
        wqa[nt] = wsq1s[o];
        sca[nt] = g[o] * rsqrtf(v[o] + EPSBN);
        moa[nt] = m[o]; boa[nt] = bb_[o];
    }

    for (int s6 = 0; s6 < 6; ++s6) {
        int j0 = s6 * 16;
        f32x4 a0[2], a1[2];
        #pragma unroll
        for (int nt = 0; nt < 2; ++nt) {
            a0[nt] = (f32x4){0.f, 0.f, 0.f, 0.f};
            a1[nt] = (f32x4){0.f, 0.f, 0.f, 0.f};
        }
        {
            int r0 = 2 * w, r1 = 2 * w + 1;
            #pragma unroll
            for (int mm = 0; mm < 4; ++mm) {
                uint2 lo0 = *(const uint2*)(xt4 + ((size_t)(r0 + kiA[mm]) * XW + j0 + l15 + kjA[mm]) * 4);
                uint2 hi0 = *(const uint2*)(xt4 + ((size_t)(r0 + kiB[mm]) * XW + j0 + l15 + kjB[mm]) * 4);
                uint2 lo1 = *(const uint2*)(xt4 + ((size_t)(r1 + kiA[mm]) * XW + j0 + l15 + kjA[mm]) * 4);
                uint2 hi1 = *(const uint2*)(xt4 + ((size_t)(r1 + kiB[mm]) * XW + j0 + l15 + kjB[mm]) * 4);
                uint4 u0; u0.x = lo0.x; u0.y = lo0.y; u0.z = hi0.x; u0.w = hi0.y;
                uint4 u1; u1.x = lo1.x; u1.y = lo1.y; u1.z = hi1.x; u1.w = hi1.y;
                bf16x8 av0 = *(bf16x8*)&u0;
                bf16x8 av1 = *(bf16x8*)&u1;
                a0[0] = __builtin_amdgcn_mfma_f32_16x16x32_bf16(av0, Bq[mm][0], a0[0], 0, 0, 0);
                a0[1] = __builtin_amdgcn_mfma_f32_16x16x32_bf16(av0, Bq[mm][1], a0[1], 0, 0, 0);
                a1[0] = __builtin_amdgcn_mfma_f32_16x16x32_bf16(av1, Bq[mm][0], a1[0], 0, 0, 0);
                a1[1] = __builtin_amdgcn_mfma_f32_16x16x32_bf16(av1, Bq[mm][1], a1[1], 0, 0, 0);
            }
        }
        #pragma unroll
        for (int q = 0; q < 2; ++q) {
            int pj = (j0 >> 1) + l4 * 2 + q;   // pooled col
            if (pj < P1) {
                #pragma unroll
                for (int nt = 0; nt < 2; ++nt) {
                    float d00 = a0[nt][2 * q]     + wqa[nt];
                    float d01 = a0[nt][2 * q + 1] + wqa[nt];
                    float d10 = a1[nt][2 * q]     + wqa[nt];
                    float d11 = a1[nt][2 * q + 1] + wqa[nt];
                    float dm = fminf(fminf(d00, d01), fminf(d10, d11));
                    float y = (__expf(-GAMMA * dm) - moa[nt]) * sca[nt] + boa[nt];
                    h1t[((size_t)b * 2116 + pi * P1 + pj) * 32 + nt * 16 + l15] = f2bf(y);
                }
            }
        }
    }
}

// ------- conv2 MFMA: r19 proven version (12-row bands, in-LDS box; closed) -------
__global__ __launch_bounds__(256, 2) void k_conv2m(
    const unsigned short* __restrict__ h1t, const unsigned short* __restrict__ w2bf,
    const float* __restrict__ wsq2,
    const float* __restrict__ g2, const float* __restrict__ b2,
    const float* __restrict__ m2, const float* __restrict__ v2,
    unsigned short* __restrict__ h2t) {
    __shared__ unsigned short lds[2304 * 8];  // 36864 B (valid 12*46*4=2208 chunks)
    __shared__ float sst[12 * 46];
    __shared__ float rh[12 * 42];
    __shared__ float xq[8 * 42];
    int b = blockIdx.y;
    int bx = blockIdx.x;             // 0..5: pooled rows 4bx..4bx+3
    int rbase = 8 * bx;
    int tid = threadIdx.x;
    {
        uint4 tmp[9];
        #pragma unroll
        for (int it = 0; it < 9; ++it) {
            int c = tid + it * 256;
            int cs = c < 2208 ? c : 2207;
            int p = cs >> 2, s = cs & 3;
            int il = p / 46, jl = p - il * 46;
            int srow = rbase + il; if (srow > 45) srow = 45;
            int src_s = (s - il - jl) & 3;  // inverse swizzle on SOURCE side
            tmp[it] = *(const uint4*)(h1t + ((((size_t)b * 46 + srow) * 46 + jl) * 32) + src_s * 8);
        }
        #pragma unroll
        for (int it = 0; it < 9; ++it) {
            int c = tid + it * 256;
            *(uint4*)(lds + (size_t)c * 8) = tmp[it];
        }
    }
    __syncthreads();
    for (int p = tid; p < 552; p += 256) {
        float s2 = 0.f;
        #pragma unroll
        for (int sl = 0; sl < 4; ++sl) {
            bf16x8 v8 = *(const bf16x8*)(lds + (size_t)p * 32 + sl * 8);
            #pragma unroll
            for (int e = 0; e < 8; ++e) {
                float yv = bf2f((unsigned short)v8[e]);
                s2 = fmaf(yv, yv, s2);
            }
        }
        sst[p] = s2;
    }
    __syncthreads();
    for (int i = tid; i < 504; i += 256) {
        int r = i / 42, j = i - r * 42;
        const float* s = &sst[r * 46 + j];
        rh[i] = s[0] + s[1] + s[2] + s[3] + s[4];
    }
    __syncthreads();
    for (int i = tid; i < 336; i += 256) {
        const float* s = &rh[i];
        xq[i] = s[0] + s[42] + s[84] + s[126] + s[168];
    }
    __syncthreads();

    int lane = tid & 63, st = tid >> 6;   // 4 waves, one pooled row each
    int prow = 4 * bx + st;
    if (prow >= P2) return;
    int hi = lane >> 5;
    int ri = lane & 1;
    int cpos = (lane >> 1) & 15;
    int ol = lane & 31;

    float wqA[2], scA[2], moA[2], boA[2];
    #pragma unroll
    for (int nt = 0; nt < 2; ++nt) {
        int o = nt * 32 + ol;
        wqA[nt] = wsq2[o];
        scA[nt] = g2[o] * rsqrtf(v2[o] + EPSBN);
        moA[nt] = m2[o]; boA[nt] = b2[o];
    }

    f32x16 acc0[3], acc1[3];
    #pragma unroll
    for (int cg = 0; cg < 3; ++cg)
        #pragma unroll
        for (int e = 0; e < 16; ++e) { acc0[cg][e] = 0.f; acc1[cg][e] = 0.f; }

    #pragma unroll 1
    for (int ks = 0; ks < 2; ++ks) {
        const unsigned short* wb0 = w2bf + (((size_t)ks * 2 + hi) * 64 + ol) * 8;
        const unsigned short* wb1 = wb0 + 32 * 8;   // o + 32
        int sB = 2 * ks + hi;
        #pragma unroll 1
        for (int ki = 0; ki < 5; ++ki) {
            bf16x8 B0[5], B1[5];
            #pragma unroll
            for (int kj = 0; kj < 5; ++kj) {
                B0[kj] = *(const bf16x8*)(wb0 + (size_t)(ki * 5 + kj) * 2048);
                B1[kj] = *(const bf16x8*)(wb1 + (size_t)(ki * 5 + kj) * 2048);
            }
            int il = 2 * st + ri + ki;   // 0..11 local row
            int base = il * 46;
            int sI = sB + il;
            #pragma unroll
            for (int cg = 0; cg < 3; ++cg) {
                #pragma unroll
                for (int kj = 0; kj < 5; ++kj) {
                    int jl = cg * 16 + cpos + kj; if (jl > 45) jl = 45;
                    int slot = (sI + jl) & 3;
                    bf16x8 av = *(const bf16x8*)(lds + (base + jl) * 32 + slot * 8);
                    acc0[cg] = __builtin_amdgcn_mfma_f32_32x32x16_bf16(av, B0[kj], acc0[cg], 0, 0, 0);
                    acc1[cg] = __builtin_amdgcn_mfma_f32_32x32x16_bf16(av, B1[kj], acc1[cg], 0, 0, 0);
                }
            }
        }
    }
    size_t bb = (size_t)b * FLAT;
    int lr = 2 * st;
    #pragma unroll
    for (int cg = 0; cg < 3; ++cg) {
        int j0 = cg * 16;
        #pragma unroll
        for (int q = 0; q < 4; ++q) {
            int wdw = 2 * q + hi;
            int pcol = cg * 8 + wdw;
            if (pcol < P2) {
                int jc = j0 + 2 * wdw;
                float x00 = xq[lr * 42 + jc],       x01 = xq[lr * 42 + jc + 1];
                float x10 = xq[(lr + 1) * 42 + jc], x11 = xq[(lr + 1) * 42 + jc + 1];
                int pp = prow * 21 + pcol;
                {
                    float d0 = x00 + acc0[cg][4 * q + 0] + wqA[0];
                    float d1 = x10 + acc0[cg][4 * q + 1] + wqA[0];
                    float d2 = x01 + acc0[cg][4 * q + 2] + wqA[0];
                    float d3 = x11 + acc0[cg][4 * q + 3] + wqA[0];
                    float dm = fminf(fminf(d0, d1), fminf(d2, d3));
                    float y = (__expf(-GAMMA * dm) - moA[0]) * scA[0] + boA[0];
                    h2t[bb + (size_t)ol * 441 + pp] = f2bf(y);
                }
                {
                    float d0 = x00 + acc1[cg][4 * q + 0] + wqA[1];
                    float d1 = x10 + acc1[cg][4 * q + 1] + wqA[1];
                    float d2 = x01 + acc1[cg][4 * q + 2] + wqA[1];
                    float d3 = x11 + acc1[cg][4 * q + 3] + wqA[1];
                    float dm = fminf(fminf(d0, d1), fminf(d2, d3));
                    float y = (__expf(-GAMMA * dm) - moA[1]) * scA[1] + boA[1];
                    h2t[bb + (size_t)(32 + ol) * 441 + pp] = f2bf(y);
                }
            }
        }
    }
}

// ------- FC1 MFMA v3: 63 K-segments, grid (63,4) = 252 blocks -------
__global__ __launch_bounds__(256) void k_fc1m(const unsigned short* __restrict__ A,
                                              const float* __restrict__ W,
                                              float* __restrict__ part) {
    __shared__ unsigned short Ws[64][456];
    int s = blockIdx.x;
    int nb = blockIdx.y;
    int n0 = nb * 64;
    int k0 = s * 448;
    int tid = threadIdx.x;
    for (int i = tid; i < 64 * 112; i += 256) {
        int n = i / 112, j = i - n * 112;
        float4 v = *(const float4*)(W + (size_t)(n0 + n) * FLAT + k0 + j * 4);
        unsigned int lo = (unsigned)f2bf(v.x) | ((unsigned)f2bf(v.y) << 16);
        unsigned int hi2 = (unsigned)f2bf(v.z) | ((unsigned)f2bf(v.w) << 16);
        uint2 pk; pk.x = lo; pk.y = hi2;
        *(uint2*)(&Ws[n][j * 4]) = pk;
    }
    __syncthreads();
    int lane = tid & 63, w = tid >> 6;
    int l15 = lane & 15, l4 = lane >> 4;
    const unsigned short* ap = A + (size_t)l15 * FLAT + k0 + l4 * 8;
    f32x4 acc[8];
    #pragma unroll
    for (int mf = 0; mf < 8; ++mf) acc[mf] = (f32x4){0.f, 0.f, 0.f, 0.f};
    #pragma unroll 2
    for (int kc = 0; kc < 14; ++kc) {
        bf16x8 Bf = *(const bf16x8*)(&Ws[w * 16 + l15][kc * 32 + l4 * 8]);
        #pragma unroll
        for (int mf = 0; mf < 8; ++mf) {
            bf16x8 Af = *(const bf16x8*)(ap + (size_t)mf * 16 * FLAT + kc * 32);
            acc[mf] = __builtin_amdgcn_mfma_f32_16x16x32_bf16(Af, Bf, acc[mf], 0, 0, 0);
        }
    }
    float* pp = part + (size_t)s * B_ * L1N;
    #pragma unroll
    for (int mf = 0; mf < 8; ++mf)
        #pragma unroll
        for (int r = 0; r < 4; ++r)
            pp[(size_t)(mf * 16 + l4 * 4 + r) * L1N + n0 + w * 16 + l15] = acc[mf][r];
}

// ------- fused FC1-reduce + FC2 + log_softmax: one block per image -------
__global__ __launch_bounds__(256) void k_fcout(const float* __restrict__ part,
                                               const float* __restrict__ fc1b,
                                               const float* __restrict__ fc2w,
                                               const float* __restrict__ fc2b,
                                               float* __restrict__ out) {
    __shared__ float a[L1N];
    __shared__ float z[16];
    int b = blockIdx.x;
    int o = threadIdx.x;
    float s = 0.f;
    for (int ks = 0; ks < 63; ++ks) s += part[(size_t)ks * B_ * L1N + (size_t)b * L1N + o];
    a[o] = fmaxf(s + fc1b[o], 0.f);
    __syncthreads();
    int lane = threadIdx.x & 63, wv = threadIdx.x >> 6;
    for (int j = wv; j < NCLS; j += 4) {
        float p = 0.f;
        for (int k = lane; k < L1N; k += 64)
            p = fmaf(a[k], fc2w[(size_t)j * L1N + k], p);
        #pragma unroll
        for (int off = 32; off; off >>= 1) p += __shfl_down(p, off, 64);
        if (lane == 0) z[j] = fmaxf(p + fc2b[j], 0.f);
    }
    __syncthreads();
    if (threadIdx.x == 0) {
        float mx = -1e30f;
        for (int j = 0; j < NCLS; ++j) mx = fmaxf(mx, z[j]);
        float ss = 0.f;
        for (int j = 0; j < NCLS; ++j) ss += expf(z[j] - mx);
        float l = logf(ss);
        for (int j = 0; j < NCLS; ++j) out[(size_t)b * NCLS + j] = z[j] - mx - l;
    }
}

extern "C" void kernel_launch(void* const* d_in, const int* in_sizes, int n_in,
                              void* d_out, int out_size, void* d_ws, size_t ws_size,
                              hipStream_t stream) {
    const float* x    = (const float*)d_in[0];
    const float* w1   = (const float*)d_in[1];
    const float* w2   = (const float*)d_in[2];
    const float* bn1g = (const float*)d_in[3];
    const float* bn1b = (const float*)d_in[4];
    const float* bn1m = (const float*)d_in[5];
    const float* bn1v = (const float*)d_in[6];
    const float* bn2g = (const float*)d_in[7];
    const float* bn2b = (const float*)d_in[8];
    const float* bn2m = (const float*)d_in[9];
    const float* bn2v = (const float*)d_in[10];
    const float* fc1w = (const float*)d_in[11];
    const float* fc1b = (const float*)d_in[12];
    const float* fc2w = (const float*)d_in[13];
    const float* fc2b = (const float*)d_in[14];
    float* out = (float*)d_out;

    char* wsb = (char*)d_ws;
    unsigned short* h1t = (unsigned short*)wsb;  wsb += (size_t)B_ * 2116 * 32 * 2;     // 17.3 MB
    unsigned short* h2t = (unsigned short*)wsb;  wsb += (size_t)B_ * FLAT * 2;          // 7.2 MB (o-major)
    float* part  = (float*)wsb;                  wsb += (size_t)63 * B_ * L1N * 4;      // 8.3 MB
    unsigned short* w2bf = (unsigned short*)wsb; wsb += (size_t)51200 * 2;
    float* wsq2 = (float*)wsb;                   wsb += 64 * 4;

    k_conv1m<<<dim3(13, B_), 256, 0, stream>>>(
        x, w1, w2, bn1g, bn1b, bn1m, bn1v, h1t, w2bf, wsq2);
    k_conv2m<<<dim3(6, B_), 256, 0, stream>>>(
        h1t, w2bf, wsq2, bn2g, bn2b, bn2m, bn2v, h2t);
    k_fc1m<<<dim3(63, 4), 256, 0, stream>>>(h2t, fc1w, part);
    k_fcout<<<B_, 256, 0, stream>>>(part, fc1b, fc2w, fc2b, out);
}

// Round 26
// 95.736 us; speedup vs baseline: 1.6442x; 1.0020x over previous
//
#include <hip/hip_runtime.h>
#include <math.h>

#define GAMMA 0.05f
#define EPSBN 1e-5f

#define B_   128
#define H0   96
#define O1   32
#define P1   46   // pooled1 (46x46), conv1 out 92x92
#define O2   64
#define H2C  42   // conv2 out spatial
#define P2   21   // pooled2
#define FLAT (O2*P2*P2)   // 28224
#define L1N  256
#define NCLS 10
#define XW   104  // padded LDS row width (positions)

typedef __attribute__((ext_vector_type(8))) short bf16x8;
typedef __attribute__((ext_vector_type(4))) float f32x4;
typedef __attribute__((ext_vector_type(16))) float f32x16;

static __device__ __forceinline__ float bf2f(unsigned short h) {
    return __uint_as_float(((unsigned int)h) << 16);
}
static __device__ __forceinline__ unsigned short f2bf(float f) {
    unsigned int u = __float_as_uint(f);
    u = (u + 0x7FFFu + ((u >> 16) & 1u)) >> 16;
    return (unsigned short)u;
}

// ------- conv1 MFMA v9: inline w1q/wsq1 prep (per block, LDS); w2bf prep in bx==12 blocks -------
// r25 post-mortem: cooperative mega-kernel fails under the harness's graph capture
// (output never written). Reverted verbatim to the r24-proven 4-kernel pipeline.
__global__ __launch_bounds__(256) void k_conv1m(
    const float* __restrict__ x, const float* __restrict__ w1, const float* __restrict__ w2,
    const float* __restrict__ g, const float* __restrict__ bb_,
    const float* __restrict__ m, const float* __restrict__ v,
    unsigned short* __restrict__ h1t,
    unsigned short* __restrict__ w2bf, float* __restrict__ wsq2) {
    int b = blockIdx.y;
    int tid = threadIdx.x;
    if (blockIdx.x == 12) {
        // weight prep for conv2m (64 active blocks)
        int pb = b;
        if (pb < 64) {
            for (int i = pb * 256 + tid; i < 51200; i += 64 * 256) {
                int e = i & 7, o = (i >> 3) & 63, hi = (i >> 9) & 1, ks = (i >> 10) & 1, kp = i >> 11;
                int ch = ks * 16 + hi * 8 + e;
                w2bf[i] = f2bf(-2.f * w2[((size_t)o * 32 + ch) * 25 + kp]);
            }
            if (pb == 0 && tid < 64) {
                const float* p = w2 + (size_t)tid * 800;
                float s = 0.f;
                for (int i = 0; i < 800; ++i) s += p[i] * p[i];
                wsq2[tid] = s;
            }
        }
        return;
    }
    __shared__ unsigned short xt4[1536 * 4];  // 12288 B (valid 13*104=1352 positions)
    __shared__ unsigned short w1qs[4096];     // 8192 B
    __shared__ float wsq1s[32];
    int pi0 = blockIdx.x * 4;
    {
        const float* xb = x + (size_t)b * 3 * 9216;
        float va[6], vc[6], vd[6];
        int ok[6];
        #pragma unroll
        for (int it = 0; it < 6; ++it) {
            int c = tid + it * 256;
            int cs = c < 1352 ? c : 1351;
            int rr = cs / XW, cc2 = cs - rr * XW;
            int srow = 2 * pi0 + rr; if (srow > 95) srow = 95;
            ok[it] = (cc2 < 96);
            int off = srow * 96 + (cc2 < 96 ? cc2 : 95);
            va[it] = xb[off];
            vc[it] = xb[9216 + off];
            vd[it] = xb[18432 + off];
        }
        #pragma unroll
        for (int it = 0; it < 6; ++it) {
            int c = tid + it * 256;
            unsigned int p0 = 0, p1 = 0;
            if (ok[it]) {
                float a = va[it], cch = vc[it], dd = vd[it];
                float s = a * a + cch * cch + dd * dd;
                p0 = (unsigned)f2bf(a) | ((unsigned)f2bf(cch) << 16);
                p1 = (unsigned)f2bf(dd) | ((unsigned)f2bf(s) << 16);
            }
            uint2 pk; pk.x = p0; pk.y = p1;
            *(uint2*)(xt4 + (size_t)c * 4) = pk;
        }
        // inline w1q prep (K repacked: 8 taps x 4 slots {x0,x1,x2,sq})
        for (int j = tid; j < 4096; j += 256) {
            int e = j & 7, o = (j >> 3) & 31, s = j >> 8;  // s 0..15
            int tap = (s >> 2) * 8 + 2 * (s & 3) + (e >> 2);
            int ch = e & 3;
            float vv = 0.f;
            if (tap < 25) {
                if (ch < 3) vv = -2.f * w1[(size_t)(o * 3 + ch) * 25 + tap];
                else vv = 1.f;
            }
            w1qs[j] = f2bf(vv);
        }
        if (tid < 32) {
            const float* p = w1 + tid * 75;
            float s = 0.f;
            for (int i = 0; i < 75; ++i) s += p[i] * p[i];
            wsq1s[tid] = s;
        }
    }
    __syncthreads();
    int w = tid >> 6, lane = tid & 63;
    int pi = pi0 + w;
    if (pi >= P1) return;
    int l15 = lane & 15, l4 = lane >> 4;

    int kiA[4], kjA[4], kiB[4], kjB[4];
    #pragma unroll
    for (int mm = 0; mm < 4; ++mm) {
        int tA = mm * 8 + 2 * l4;
        int tB = tA + 1;
        kiA[mm] = (tA < 25) ? tA / 5 : 4;  kjA[mm] = (tA < 25) ? tA % 5 : 4;
        kiB[mm] = (tB < 25) ? tB / 5 : 4;  kjB[mm] = (tB < 25) ? tB % 5 : 4;
    }
    bf16x8 Bq[4][2];
    #pragma unroll
    for (int mm = 0; mm < 4; ++mm)
        #pragma unroll
        for (int nt = 0; nt < 2; ++nt)
            Bq[mm][nt] = *(const bf16x8*)(&w1qs[(((size_t)(mm * 4 + l4)) * 32 + nt * 16 + l15) * 8]);

    float wqa[2], sca[2], moa[2], boa[2];
    #pragma unroll
    for (int nt = 0; nt < 2; ++nt) {
        int o = nt * 16 + l15;
        wqa[nt] = wsq1s[o];
        sca[nt] = g[o] * rsqrtf(v[o] + EPSBN);
        moa[nt] = m[o]; boa[nt] = bb_[o];
    }

    for (int s6 = 0; s6 < 6; ++s6) {
        int j0 = s6 * 16;
        f32x4 a0[2], a1[2];
        #pragma unroll
        for (int nt = 0; nt < 2; ++nt) {
            a0[nt] = (f32x4){0.f, 0.f, 0.f, 0.f};
            a1[nt] = (f32x4){0.f, 0.f, 0.f, 0.f};
        }
        {
            int r0 = 2 * w, r1 = 2 * w + 1;
            #pragma unroll
            for (int mm = 0; mm < 4; ++mm) {
                uint2 lo0 = *(const uint2*)(xt4 + ((size_t)(r0 + kiA[mm]) * XW + j0 + l15 + kjA[mm]) * 4);
                uint2 hi0 = *(const uint2*)(xt4 + ((size_t)(r0 + kiB[mm]) * XW + j0 + l15 + kjB[mm]) * 4);
                uint2 lo1 = *(const uint2*)(xt4 + ((size_t)(r1 + kiA[mm]) * XW + j0 + l15 + kjA[mm]) * 4);
                uint2 hi1 = *(const uint2*)(xt4 + ((size_t)(r1 + kiB[mm]) * XW + j0 + l15 + kjB[mm]) * 4);
                uint4 u0; u0.x = lo0.x; u0.y = lo0.y; u0.z = hi0.x; u0.w = hi0.y;
                uint4 u1; u1.x = lo1.x; u1.y = lo1.y; u1.z = hi1.x; u1.w = hi1.y;
                bf16x8 av0 = *(bf16x8*)&u0;
                bf16x8 av1 = *(bf16x8*)&u1;
                a0[0] = __builtin_amdgcn_mfma_f32_16x16x32_bf16(av0, Bq[mm][0], a0[0], 0, 0, 0);
                a0[1] = __builtin_amdgcn_mfma_f32_16x16x32_bf16(av0, Bq[mm][1], a0[1], 0, 0, 0);
                a1[0] = __builtin_amdgcn_mfma_f32_16x16x32_bf16(av1, Bq[mm][0], a1[0], 0, 0, 0);
                a1[1] = __builtin_amdgcn_mfma_f32_16x16x32_bf16(av1, Bq[mm][1], a1[1], 0, 0, 0);
            }
        }
        #pragma unroll
        for (int q = 0; q < 2; ++q) {
            int pj = (j0 >> 1) + l4 * 2 + q;   // pooled col
            if (pj < P1) {
                #pragma unroll
                for (int nt = 0; nt < 2; ++nt) {
                    float d00 = a0[nt][2 * q]     + wqa[nt];
                    float d01 = a0[nt][2 * q + 1] + wqa[nt];
                    float d10 = a1[nt][2 * q]     + wqa[nt];
                    float d11 = a1[nt][2 * q + 1] + wqa[nt];
                    float dm = fminf(fminf(d00, d01), fminf(d10, d11));
                    float y = (__expf(-GAMMA * dm) - moa[nt]) * sca[nt] + boa[nt];
                    h1t[((size_t)b * 2116 + pi * P1 + pj) * 32 + nt * 16 + l15] = f2bf(y);
                }
            }
        }
    }
}

// ------- conv2 MFMA: r19 proven version (12-row bands, in-LDS box; closed) -------
__global__ __launch_bounds__(256, 2) void k_conv2m(
    const unsigned short* __restrict__ h1t, const unsigned short* __restrict__ w2bf,
    const float* __restrict__ wsq2,
    const float* __restrict__ g2, const float* __restrict__ b2,
    const float* __restrict__ m2, const float* __restrict__ v2,
    unsigned short* __restrict__ h2t) {
    __shared__ unsigned short lds[2304 * 8];  // 36864 B (valid 12*46*4=2208 chunks)
    __shared__ float sst[12 * 46];
    __shared__ float rh[12 * 42];
    __shared__ float xq[8 * 42];
    int b = blockIdx.y;
    int bx = blockIdx.x;             // 0..5: pooled rows 4bx..4bx+3
    int rbase = 8 * bx;
    int tid = threadIdx.x;
    {
        uint4 tmp[9];
        #pragma unroll
        for (int it = 0; it < 9; ++it) {
            int c = tid + it * 256;
            int cs = c < 2208 ? c : 2207;
            int p = cs >> 2, s = cs & 3;
            int il = p / 46, jl = p - il * 46;
            int srow = rbase + il; if (srow > 45) srow = 45;
            int src_s = (s - il - jl) & 3;  // inverse swizzle on SOURCE side
            tmp[it] = *(const uint4*)(h1t + ((((size_t)b * 46 + srow) * 46 + jl) * 32) + src_s * 8);
        }
        #pragma unroll
        for (int it = 0; it < 9; ++it) {
            int c = tid + it * 256;
            *(uint4*)(lds + (size_t)c * 8) = tmp[it];
        }
    }
    __syncthreads();
    for (int p = tid; p < 552; p += 256) {
        float s2 = 0.f;
        #pragma unroll
        for (int sl = 0; sl < 4; ++sl) {
            bf16x8 v8 = *(const bf16x8*)(lds + (size_t)p * 32 + sl * 8);
            #pragma unroll
            for (int e = 0; e < 8; ++e) {
                float yv = bf2f((unsigned short)v8[e]);
                s2 = fmaf(yv, yv, s2);
            }
        }
        sst[p] = s2;
    }
    __syncthreads();
    for (int i = tid; i < 504; i += 256) {
        int r = i / 42, j = i - r * 42;
        const float* s = &sst[r * 46 + j];
        rh[i] = s[0] + s[1] + s[2] + s[3] + s[4];
    }
    __syncthreads();
    for (int i = tid; i < 336; i += 256) {
        const float* s = &rh[i];
        xq[i] = s[0] + s[42] + s[84] + s[126] + s[168];
    }
    __syncthreads();

    int lane = tid & 63, st = tid >> 6;   // 4 waves, one pooled row each
    int prow = 4 * bx + st;
    if (prow >= P2) return;
    int hi = lane >> 5;
    int ri = lane & 1;
    int cpos = (lane >> 1) & 15;
    int ol = lane & 31;

    float wqA[2], scA[2], moA[2], boA[2];
    #pragma unroll
    for (int nt = 0; nt < 2; ++nt) {
        int o = nt * 32 + ol;
        wqA[nt] = wsq2[o];
        scA[nt] = g2[o] * rsqrtf(v2[o] + EPSBN);
        moA[nt] = m2[o]; boA[nt] = b2[o];
    }

    f32x16 acc0[3], acc1[3];
    #pragma unroll
    for (int cg = 0; cg < 3; ++cg)
        #pragma unroll
        for (int e = 0; e < 16; ++e) { acc0[cg][e] = 0.f; acc1[cg][e] = 0.f; }

    #pragma unroll 1
    for (int ks = 0; ks < 2; ++ks) {
        const unsigned short* wb0 = w2bf + (((size_t)ks * 2 + hi) * 64 + ol) * 8;
        const unsigned short* wb1 = wb0 + 32 * 8;   // o + 32
        int sB = 2 * ks + hi;
        #pragma unroll 1
        for (int ki = 0; ki < 5; ++ki) {
            bf16x8 B0[5], B1[5];
            #pragma unroll
            for (int kj = 0; kj < 5; ++kj) {
                B0[kj] = *(const bf16x8*)(wb0 + (size_t)(ki * 5 + kj) * 2048);
                B1[kj] = *(const bf16x8*)(wb1 + (size_t)(ki * 5 + kj) * 2048);
            }
            int il = 2 * st + ri + ki;   // 0..11 local row
            int base = il * 46;
            int sI = sB + il;
            #pragma unroll
            for (int cg = 0; cg < 3; ++cg) {
                #pragma unroll
                for (int kj = 0; kj < 5; ++kj) {
                    int jl = cg * 16 + cpos + kj; if (jl > 45) jl = 45;
                    int slot = (sI + jl) & 3;
                    bf16x8 av = *(const bf16x8*)(lds + (base + jl) * 32 + slot * 8);
                    acc0[cg] = __builtin_amdgcn_mfma_f32_32x32x16_bf16(av, B0[kj], acc0[cg], 0, 0, 0);
                    acc1[cg] = __builtin_amdgcn_mfma_f32_32x32x16_bf16(av, B1[kj], acc1[cg], 0, 0, 0);
                }
            }
        }
    }
    size_t bb = (size_t)b * FLAT;
    int lr = 2 * st;
    #pragma unroll
    for (int cg = 0; cg < 3; ++cg) {
        int j0 = cg * 16;
        #pragma unroll
        for (int q = 0; q < 4; ++q) {
            int wdw = 2 * q + hi;
            int pcol = cg * 8 + wdw;
            if (pcol < P2) {
                int jc = j0 + 2 * wdw;
                float x00 = xq[lr * 42 + jc],       x01 = xq[lr * 42 + jc + 1];
                float x10 = xq[(lr + 1) * 42 + jc], x11 = xq[(lr + 1) * 42 + jc + 1];
                int pp = prow * 21 + pcol;
                {
                    float d0 = x00 + acc0[cg][4 * q + 0] + wqA[0];
                    float d1 = x10 + acc0[cg][4 * q + 1] + wqA[0];
                    float d2 = x01 + acc0[cg][4 * q + 2] + wqA[0];
                    float d3 = x11 + acc0[cg][4 * q + 3] + wqA[0];
                    float dm = fminf(fminf(d0, d1), fminf(d2, d3));
                    float y = (__expf(-GAMMA * dm) - moA[0]) * scA[0] + boA[0];
                    h2t[bb + (size_t)ol * 441 + pp] = f2bf(y);
                }
                {
                    float d0 = x00 + acc1[cg][4 * q + 0] + wqA[1];
                    float d1 = x10 + acc1[cg][4 * q + 1] + wqA[1];
                    float d2 = x01 + acc1[cg][4 * q + 2] + wqA[1];
                    float d3 = x11 + acc1[cg][4 * q + 3] + wqA[1];
                    float dm = fminf(fminf(d0, d1), fminf(d2, d3));
                    float y = (__expf(-GAMMA * dm) - moA[1]) * scA[1] + boA[1];
                    h2t[bb + (size_t)(32 + ol) * 441 + pp] = f2bf(y);
                }
            }
        }
    }
}

// ------- FC1 MFMA v3: 63 K-segments, grid (63,4) = 252 blocks -------
__global__ __launch_bounds__(256) void k_fc1m(const unsigned short* __restrict__ A,
                                              const float* __restrict__ W,
                                              float* __restrict__ part) {
    __shared__ unsigned short Ws[64][456];
    int s = blockIdx.x;
    int nb = blockIdx.y;
    int n0 = nb * 64;
    int k0 = s * 448;
    int tid = threadIdx.x;
    for (int i = tid; i < 64 * 112; i += 256) {
        int n = i / 112, j = i - n * 112;
        float4 v = *(const float4*)(W + (size_t)(n0 + n) * FLAT + k0 + j * 4);
        unsigned int lo = (unsigned)f2bf(v.x) | ((unsigned)f2bf(v.y) << 16);
        unsigned int hi2 = (unsigned)f2bf(v.z) | ((unsigned)f2bf(v.w) << 16);
        uint2 pk; pk.x = lo; pk.y = hi2;
        *(uint2*)(&Ws[n][j * 4]) = pk;
    }
    __syncthreads();
    int lane = tid & 63, w = tid >> 6;
    int l15 = lane & 15, l4 = lane >> 4;
    const unsigned short* ap = A + (size_t)l15 * FLAT + k0 + l4 * 8;
    f32x4 acc[8];
    #pragma unroll
    for (int mf = 0; mf < 8; ++mf) acc[mf] = (f32x4){0.f, 0.f, 0.f, 0.f};
    #pragma unroll 2
    for (int kc = 0; kc < 14; ++kc) {
        bf16x8 Bf = *(const bf16x8*)(&Ws[w * 16 + l15][kc * 32 + l4 * 8]);
        #pragma unroll
        for (int mf = 0; mf < 8; ++mf) {
            bf16x8 Af = *(const bf16x8*)(ap + (size_t)mf * 16 * FLAT + kc * 32);
            acc[mf] = __builtin_amdgcn_mfma_f32_16x16x32_bf16(Af, Bf, acc[mf], 0, 0, 0);
        }
    }
    float* pp = part + (size_t)s * B_ * L1N;
    #pragma unroll
    for (int mf = 0; mf < 8; ++mf)
        #pragma unroll
        for (int r = 0; r < 4; ++r)
            pp[(size_t)(mf * 16 + l4 * 4 + r) * L1N + n0 + w * 16 + l15] = acc[mf][r];
}

// ------- fused FC1-reduce + FC2 + log_softmax: one block per image -------
__global__ __launch_bounds__(256) void k_fcout(const float* __restrict__ part,
                                               const float* __restrict__ fc1b,
                                               const float* __restrict__ fc2w,
                                               const float* __restrict__ fc2b,
                                               float* __restrict__ out) {
    __shared__ float a[L1N];
    __shared__ float z[16];
    int b = blockIdx.x;
    int o = threadIdx.x;
    float s = 0.f;
    for (int ks = 0; ks < 63; ++ks) s += part[(size_t)ks * B_ * L1N + (size_t)b * L1N + o];
    a[o] = fmaxf(s + fc1b[o], 0.f);
    __syncthreads();
    int lane = threadIdx.x & 63, wv = threadIdx.x >> 6;
    for (int j = wv; j < NCLS; j += 4) {
        float p = 0.f;
        for (int k = lane; k < L1N; k += 64)
            p = fmaf(a[k], fc2w[(size_t)j * L1N + k], p);
        #pragma unroll
        for (int off = 32; off; off >>= 1) p += __shfl_down(p, off, 64);
        if (lane == 0) z[j] = fmaxf(p + fc2b[j], 0.f);
    }
    __syncthreads();
    if (threadIdx.x == 0) {
        float mx = -1e30f;
        for (int j = 0; j < NCLS; ++j) mx = fmaxf(mx, z[j]);
        float ss = 0.f;
        for (int j = 0; j < NCLS; ++j) ss += expf(z[j] - mx);
        float l = logf(ss);
        for (int j = 0; j < NCLS; ++j) out[(size_t)b * NCLS + j] = z[j] - mx - l;
    }
}

extern "C" void kernel_launch(void* const* d_in, const int* in_sizes, int n_in,
                              void* d_out, int out_size, void* d_ws, size_t ws_size,
                              hipStream_t stream) {
    const float* x    = (const float*)d_in[0];
    const float* w1   = (const float*)d_in[1];
    const float* w2   = (const float*)d_in[2];
    const float* bn1g = (const float*)d_in[3];
    const float* bn1b = (const float*)d_in[4];
    const float* bn1m = (const float*)d_in[5];
    const float* bn1v = (const float*)d_in[6];
    const float* bn2g = (const float*)d_in[7];
    const float* bn2b = (const float*)d_in[8];
    const float* bn2m = (const float*)d_in[9];
    const float* bn2v = (const float*)d_in[10];
    const float* fc1w = (const float*)d_in[11];
    const float* fc1b = (const float*)d_in[12];
    const float* fc2w = (const float*)d_in[13];
    const float* fc2b = (const float*)d_in[14];
    float* out = (float*)d_out;

    char* wsb = (char*)d_ws;
    unsigned short* h1t = (unsigned short*)wsb;  wsb += (size_t)B_ * 2116 * 32 * 2;     // 17.3 MB
    unsigned short* h2t = (unsigned short*)wsb;  wsb += (size_t)B_ * FLAT * 2;          // 7.2 MB (o-major)
    float* part  = (float*)wsb;                  wsb += (size_t)63 * B_ * L1N * 4;      // 8.3 MB
    unsigned short* w2bf = (unsigned short*)wsb; wsb += (size_t)51200 * 2;
    float* wsq2 = (float*)wsb;                   wsb += 64 * 4;

    k_conv1m<<<dim3(13, B_), 256, 0, stream>>>(
        x, w1, w2, bn1g, bn1b, bn1m, bn1v, h1t, w2bf, wsq2);
    k_conv2m<<<dim3(6, B_), 256, 0, stream>>>(
        h1t, w2bf, wsq2, bn2g, bn2b, bn2m, bn2v, h2t);
    k_fc1m<<<dim3(63, 4), 256, 0, stream>>>(h2t, fc1w, part);
    k_fcout<<<B_, 256, 0, stream>>>(part, fc1b, fc2w, fc2b, out);
}